// Round 1
// baseline (795.062 us; speedup 1.0000x reference)
//
#include <hip/hip_runtime.h>

#define BB 16384
#define NN 32
#define DD 256
#define CC 128
#define HH 8
#define ALPHA 0.2f

// Persistent-block geometry
#define GRID 2048
#define NPB 8                  // nodes per block; GRID*NPB == BB

// LDS geometry
#define SA_STRIDE 264          // bf16 elems per row (256 + 8 pad); 528 B, 16B-aligned
#define SP_STRIDE 56           // bf16 elems per neigh_pT row (32 + 24 pad); 112 B = 28 dwords -> 2-way (free)
#define SA_BYTES (33 * SA_STRIDE * 2)   // 17424
#define SP_BYTES (CC * SP_STRIDE * 2)   // 14336
#define OFF_SP   SA_BYTES               // 17424 (16B aligned)
#define OFF_CF   (OFF_SP + SP_BYTES)    // 31760 (16B aligned)
#define OFF_DST  (OFF_CF + 1024)        // 32784
#define OFF_SRC  (OFF_DST + 1024)       // 33808
#define SMEM_TOT (OFF_SRC + 32)         // 33840 -> 4 blocks/CU

typedef __attribute__((ext_vector_type(8))) short bf16x8;
typedef __attribute__((ext_vector_type(4))) float f32x4;

// fp32 -> bf16 bits, round-to-nearest-even
__device__ __forceinline__ unsigned short f2b(float x) {
    unsigned int u = __float_as_uint(x);
    return (unsigned short)((u + 0x7fffu + ((u >> 16) & 1u)) >> 16);
}
__device__ __forceinline__ uint2 pack4(float a, float b, float c, float d) {
    uint2 r;
    r.x = (unsigned)f2b(a) | ((unsigned)f2b(b) << 16);
    r.y = (unsigned)f2b(c) | ((unsigned)f2b(d) << 16);
    return r;
}

// ---------------------------------------------------------------------------
// Prep kernel: build MFMA B-fragment-ordered constant tables in d_ws.
//  kfrag (ws+0, 65536 B):  kern bf16, frag addr ((nt*8+ks)*64+lane)*8+j
//                          value = kern[k=ks*32+(lane>>4)*8+j][c=nt*16+(lane&15)]
//  sfrag (ws+65536, 8192 B): [Kad | Kas] (256x16) same layout (single n-tile)
//                          col<8 -> Kad[k][col] = sum_c kern[k][c]*attn[col][C+c]
//                          col>=8-> Kas[k][col-8] = sum_c kern[k][c]*attn[col-8][c]
// Grid: 18 blocks x 256. Blocks 0..15 -> kfrag, 16..17 -> sfrag.
// ---------------------------------------------------------------------------
__global__ __launch_bounds__(256) void prep_kernel(const float* __restrict__ kern,
                                                   const float* __restrict__ attn,
                                                   unsigned short* __restrict__ kfrag,
                                                   unsigned short* __restrict__ sfrag) {
    if (blockIdx.x < 16) {
        int tid = blockIdx.x * 256 + threadIdx.x;    // 0..4095
        int nt   = tid >> 9;
        int ks   = (tid >> 6) & 7;
        int lane = tid & 63;
        int q    = lane >> 4;
        int cc   = lane & 15;
        int c    = nt * 16 + cc;
        unsigned short v[8];
#pragma unroll
        for (int j = 0; j < 8; ++j) {
            int k = ks * 32 + q * 8 + j;
            v[j] = f2b(kern[k * CC + c]);
        }
        uint4* dst = (uint4*)(kfrag + ((size_t)(nt * 8 + ks) * 64 + lane) * 8);
        uint4 pk;
        pk.x = (unsigned)v[0] | ((unsigned)v[1] << 16);
        pk.y = (unsigned)v[2] | ((unsigned)v[3] << 16);
        pk.z = (unsigned)v[4] | ((unsigned)v[5] << 16);
        pk.w = (unsigned)v[6] | ((unsigned)v[7] << 16);
        *dst = pk;
    } else {
        int sid = (blockIdx.x - 16) * 256 + threadIdx.x;  // 0..511
        int ks   = sid >> 6;
        int lane = sid & 63;
        int q    = lane >> 4;
        int cc   = lane & 15;
        unsigned short v[8];
#pragma unroll
        for (int j = 0; j < 8; ++j) {
            int k = ks * 32 + q * 8 + j;
            const float* krow = kern + (size_t)k * CC;
            const float* arow = (cc < 8) ? (attn + cc * (2 * CC) + CC)
                                         : (attn + (cc - 8) * (2 * CC));
            float s0 = 0.f, s1 = 0.f;
#pragma unroll 4
            for (int c = 0; c < CC; c += 2) {
                s0 += krow[c] * arow[c];
                s1 += krow[c + 1] * arow[c + 1];
            }
            v[j] = f2b(s0 + s1);
        }
        uint4* dst = (uint4*)(sfrag + ((size_t)ks * 64 + lane) * 8);
        uint4 pk;
        pk.x = (unsigned)v[0] | ((unsigned)v[1] << 16);
        pk.y = (unsigned)v[2] | ((unsigned)v[3] << 16);
        pk.z = (unsigned)v[4] | ((unsigned)v[5] << 16);
        pk.w = (unsigned)v[6] | ((unsigned)v[7] << 16);
        *dst = pk;
    }
}

// ---------------------------------------------------------------------------
// Main fused kernel, persistent-pipelined: 2048 blocks x 8 nodes each.
// Per node: sA rows 0..31 = neigh (bf16), row 32 = node (rows 33..47 of the
// phase-3 mt=2 tile read garbage beyond sA into sP space; results discarded).
//   scores  : A(rows 0..32) @ [Kad|Kas]  -> MFMA (3 M-tiles, waves 0..2)
//   neigh_p : A(rows 0..31) @ kern       -> MFMA (2 M-tiles x 8 N-tiles), ->sP^T bf16
//   softmax : fp32 VALU, coef -> B-fragment layout (cfrag)
//   z^T     : sP^T @ cfrag               -> MFMA (8 M-tiles), +bias, float4 store
// Pipeline: while computing node i, the 9 float4/thread for node i+1 are in
// flight to registers (issued before phase 3, consumed after the post-MFMA
// barrier) -> HBM fetch overlaps MFMA/softmax instead of serializing.
// LDS 33840 B -> 4 blocks/CU.
// ---------------------------------------------------------------------------
__global__ __launch_bounds__(256) void gat_kernel(const float* __restrict__ node,
                                                  const float* __restrict__ neigh,
                                                  const float* __restrict__ bias,
                                                  const unsigned short* __restrict__ kfrag,
                                                  const unsigned short* __restrict__ sfrag,
                                                  float* __restrict__ out) {
    const int t    = threadIdx.x;
    const int lane = t & 63;
    const int wave = t >> 6;
    const int q    = lane >> 4;
    const int m15  = lane & 15;

    __shared__ __align__(16) char smem[SMEM_TOT];
    unsigned short* sA    = (unsigned short*)smem;
    unsigned short* sP    = (unsigned short*)(smem + OFF_SP);
    unsigned short* cfrag = (unsigned short*)(smem + OFF_CF);
    float*          sDst  = (float*)(smem + OFF_DST);
    float*          sSrc  = (float*)(smem + OFF_SRC);

    const int base = blockIdx.x * NPB;

    // Hoisted: zero half of cfrag (B-frag cols 8..15) is loop-invariant.
    {
        int h = t >> 5, n = t & 31;
        int l1 = (n >> 3) * 16 + h;
        cfrag[(l1 + 8) * 8 + (n & 7)] = 0;
    }

    float4 r[9];

    // ---- Prologue: stage node 'base' (batched issue: 9 loads in flight) ----
    {
        const float4* nb4 = (const float4*)(neigh + (size_t)base * (NN * DD));
        const float4* nd4 = (const float4*)(node + (size_t)base * DD);
#pragma unroll
        for (int u = 0; u < 9; ++u) {
            int j = t + (u << 8);
            if (j < 33 * 64) {
                int row = j >> 6, d4 = j & 63;
                r[u] = (row < 32) ? nb4[row * 64 + d4] : nd4[d4];
            }
        }
#pragma unroll
        for (int u = 0; u < 9; ++u) {
            int j = t + (u << 8);
            if (j < 33 * 64) {
                int row = j >> 6, d4 = j & 63;
                *(uint2*)(sA + row * SA_STRIDE + d4 * 4) = pack4(r[u].x, r[u].y, r[u].z, r[u].w);
            }
        }
    }
    __syncthreads();

    for (int i = 0; i < NPB; ++i) {
        const int b = base + i;

        // ---- Issue prefetch for node b+1 into registers (no wait) ----
        if (i + 1 < NPB) {
            const float4* nb4 = (const float4*)(neigh + (size_t)(b + 1) * (NN * DD));
            const float4* nd4 = (const float4*)(node + (size_t)(b + 1) * DD);
#pragma unroll
            for (int u = 0; u < 9; ++u) {
                int j = t + (u << 8);
                if (j < 33 * 64) {
                    int row = j >> 6, d4 = j & 63;
                    r[u] = (row < 32) ? nb4[row * 64 + d4] : nd4[d4];
                }
            }
        }

        // ---- Phase 3: scores via MFMA. waves 0..2 take M-tile = wave ----
        if (wave < 3) {
            const int mt = wave;
            f32x4 acc = {0.f, 0.f, 0.f, 0.f};
            const unsigned short* abase = sA + (mt * 16 + m15) * SA_STRIDE + q * 8;
#pragma unroll
            for (int ks = 0; ks < 8; ++ks) {
                bf16x8 bfr = *(const bf16x8*)(sfrag + ((size_t)ks * 64 + lane) * 8);
                bf16x8 afr = *(const bf16x8*)(abase + ks * 32);
                acc = __builtin_amdgcn_mfma_f32_16x16x32_bf16(afr, bfr, acc, 0, 0, 0);
            }
#pragma unroll
            for (int rr = 0; rr < 4; ++rr) {
                int row = mt * 16 + q * 4 + rr;
                if (row < 32 && m15 < 8) sDst[row * 8 + m15] = acc[rr];
                if (row == 32 && m15 >= 8) sSrc[m15 - 8] = acc[rr];
            }
        }

        // ---- Phase 1: neigh_p; each wave: N-tiles {2w, 2w+1}, M-tiles 0..1 ----
#pragma unroll
        for (int nti = 0; nti < 2; ++nti) {
            const int nt = wave * 2 + nti;
            bf16x8 kb[8];
#pragma unroll
            for (int ks = 0; ks < 8; ++ks)
                kb[ks] = *(const bf16x8*)(kfrag + ((size_t)(nt * 8 + ks) * 64 + lane) * 8);
#pragma unroll
            for (int mt = 0; mt < 2; ++mt) {
                f32x4 acc = {0.f, 0.f, 0.f, 0.f};
                const unsigned short* abase = sA + (mt * 16 + m15) * SA_STRIDE + q * 8;
#pragma unroll
                for (int ks = 0; ks < 8; ++ks) {
                    bf16x8 afr = *(const bf16x8*)(abase + ks * 32);
                    acc = __builtin_amdgcn_mfma_f32_16x16x32_bf16(afr, kb[ks], acc, 0, 0, 0);
                }
                // transpose-store: lane col c = nt*16+m15 fixed; 4 consecutive n
                int c  = nt * 16 + m15;
                int n0 = mt * 16 + q * 4;
                *(uint2*)(sP + c * SP_STRIDE + n0) = pack4(acc[0], acc[1], acc[2], acc[3]);
            }
        }
        __syncthreads();

        // ---- Phase 4: softmax over n (fp32). thread t -> h = t>>5, n = t&31 ----
        {
            int h = t >> 5, n = t & 31;
            float sc = sSrc[h] + sDst[n * 8 + h];
            sc = fmaxf(sc, ALPHA * sc);              // leaky relu
            float m = sc;
#pragma unroll
            for (int off = 16; off >= 1; off >>= 1) m = fmaxf(m, __shfl_xor(m, off, 32));
            float e = expf(sc - m);
            float den = e;
#pragma unroll
            for (int off = 16; off >= 1; off >>= 1) den += __shfl_xor(den, off, 32);
            float coef = e / den;
            int l1 = (n >> 3) * 16 + h;              // cols 0..7: coef
            cfrag[l1 * 8 + (n & 7)] = f2b(coef);
        }

        // ---- Drain prefetch: pack + store node b+1 into sA (reads of node b done) ----
        if (i + 1 < NPB) {
#pragma unroll
            for (int u = 0; u < 9; ++u) {
                int j = t + (u << 8);
                if (j < 33 * 64) {
                    int row = j >> 6, d4 = j & 63;
                    *(uint2*)(sA + row * SA_STRIDE + d4 * 4) = pack4(r[u].x, r[u].y, r[u].z, r[u].w);
                }
            }
        }
        __syncthreads();

        // ---- Phase 5: z^T = sP^T @ coef. wave handles M-tiles {2w, 2w+1} ----
        {
            bf16x8 cb = *(const bf16x8*)(cfrag + (size_t)lane * 8);
            f32x4 zero = {0.f, 0.f, 0.f, 0.f};
#pragma unroll
            for (int ii = 0; ii < 2; ++ii) {
                int mt5 = wave * 2 + ii;
                bf16x8 afr = *(const bf16x8*)(sP + (mt5 * 16 + m15) * SP_STRIDE + q * 8);
                f32x4 acc = __builtin_amdgcn_mfma_f32_16x16x32_bf16(afr, cb, zero, 0, 0, 0);
                if (m15 < 8) {                        // col = h; cols 8..15 are zero-pad
                    int h  = m15;
                    int c0 = mt5 * 16 + q * 4;
                    float4 bv = *(const float4*)(bias + h * CC + c0);
                    float4 rv;
                    rv.x = acc[0] + bv.x;
                    rv.y = acc[1] + bv.y;
                    rv.z = acc[2] + bv.z;
                    rv.w = acc[3] + bv.w;
                    *(float4*)(out + (size_t)b * (HH * CC) + h * CC + c0) = rv;
                }
            }
        }
        __syncthreads();
    }
}

extern "C" void kernel_launch(void* const* d_in, const int* in_sizes, int n_in,
                              void* d_out, int out_size, void* d_ws, size_t ws_size,
                              hipStream_t stream) {
    const float* node  = (const float*)d_in[0];   // (B, D)
    const float* neigh = (const float*)d_in[1];   // (B, N, D)
    const float* kern  = (const float*)d_in[2];   // (D, C)
    const float* attn  = (const float*)d_in[3];   // (1, H, 2C)
    const float* bias  = (const float*)d_in[4];   // (H*C,)
    float* out = (float*)d_out;                   // (1, B, H*C)

    unsigned short* kfrag = (unsigned short*)d_ws;                  // 65536 B
    unsigned short* sfrag = (unsigned short*)((char*)d_ws + 65536); // 8192 B

    hipLaunchKernelGGL(prep_kernel, dim3(18), dim3(256), 0, stream, kern, attn, kfrag, sfrag);
    hipLaunchKernelGGL(gat_kernel, dim3(GRID), dim3(256), 0, stream,
                       node, neigh, bias, kfrag, sfrag, out);
}